// Round 1
// baseline (5421.854 us; speedup 1.0000x reference)
//
#include <hip/hip_runtime.h>
#include <math.h>

#define NTHREADS 512

// ---- LDS float offsets (one extern __shared__ arena) ----
#define OFF_U    0            // 64
#define OFF_IT   64           // 64
#define OFF_B1   128          // 32
#define OFF_RB   160          // 160 (5 layers x 32)
#define OFF_PW   320          // 32
#define OFF_PB   352          // 1  (pad to 384)
#define OFF_W    384          // 16384: current layer weights [ci][a][co][dj]
#define OFF_T    (OFF_W + 16384)    // 16768: T[ci][a][j]  (4096)
#define OFF_X1   (OFF_T + 4096)     // 20864: conv1 strip [ci][r][34] col-padded (4352)
#define OFF_X2   (OFF_X1 + 4352)    // 25216: conv2 out padded [32][18][18] (10368)
#define SMEM_FLOATS (OFF_X2 + 10368)  // 35584 -> 142336 bytes
#define SMEM_BYTES  (SMEM_FLOATS * 4)
// aliased regions (T/X1 dead after the strip loop):
#define OFF_X3   OFF_T              // [32][10][10] = 3200  (fits in T's 4096)
#define OFF_X4   OFF_X1             // [32][6][6]   = 1152
#define OFF_X5   (OFF_X1 + 1152)    // [32][4][4]   = 512
#define OFF_X6   (OFF_X1 + 1664)    // [32]

__device__ __forceinline__ void stageW(float* sm, int t, const float* __restrict__ rwg, int L) {
    // global rest_w layout: [L][co][ci][a][dj]; LDS layout: [ci][a][co][dj]
    for (int g = t; g < 16384; g += NTHREADS) {
        int k  = g & 15;          // a*4+dj
        int ci = (g >> 4) & 31;
        int co = g >> 9;
        sm[OFF_W + ((ci * 4 + (k >> 2)) * 32 + co) * 4 + (k & 3)] = rwg[L * 16384 + g];
    }
}

template <int OUTN, int INP>
__device__ __forceinline__ void convL(float* sm, int t, int inOff, int outOff, int bOff) {
    constexpr int TOTAL = 32 * OUTN * OUTN;
    for (int v = t; v < TOTAL; v += NTHREADS) {
        int qq = v % OUTN;
        int pp = (v / OUTN) % OUTN;
        int co = v / (OUTN * OUTN);
        float acc = sm[OFF_RB + bOff + co];
        for (int ci = 0; ci < 32; ++ci) {
#pragma unroll
            for (int a = 0; a < 4; ++a) {
                const float* wb = &sm[OFF_W + ((ci * 4 + a) * 32 + co) * 4];
                const float* xb = &sm[inOff + (ci * INP + 2 * pp + a) * INP + 2 * qq];
                float4 wv = *(const float4*)wb;      // 16B aligned
                float2 x0 = *(const float2*)(xb);    // 8B aligned (2*qq even)
                float2 x1 = *(const float2*)(xb + 2);
                acc = fmaf(wv.x, x0.x, acc);
                acc = fmaf(wv.y, x0.y, acc);
                acc = fmaf(wv.z, x1.x, acc);
                acc = fmaf(wv.w, x1.y, acc);
            }
        }
        float val = fmaxf(acc, 0.f);
        if constexpr (OUTN == 1) {
            sm[outOff + co] = val;
        } else {
            sm[outOff + (co * (OUTN + 2) + pp + 1) * (OUTN + 2) + qq + 1] = val;
        }
    }
}

__global__ void __launch_bounds__(NTHREADS, 1)
convncf_fused(const int* __restrict__ user,
              const int* __restrict__ item_pos,
              const int* __restrict__ item_neg,
              const float* __restrict__ uemb,
              const float* __restrict__ iemb,
              const float* __restrict__ w1g,
              const float* __restrict__ b1g,
              const float* __restrict__ rwg,
              const float* __restrict__ rbg,
              const float* __restrict__ pwg,
              const float* __restrict__ pbg,
              float* __restrict__ out,
              int B)
{
    extern __shared__ float sm[];
    const int t = threadIdx.x;
    const int s = blockIdx.x;
    const int branch = blockIdx.y;

    const int uidx = user[s];
    const int iidx = branch ? item_neg[s] : item_pos[s];

    // ---- init: embeddings, small consts, zero padded buffers, stage conv2 weights ----
    if (t < 64)        sm[OFF_U + t]          = uemb[(long)uidx * 64 + t];
    else if (t < 128)  sm[OFF_IT + (t - 64)]  = iemb[(long)iidx * 64 + (t - 64)];
    else if (t < 160)  sm[OFF_B1 + (t - 128)] = b1g[t - 128];
    else if (t < 320)  sm[OFF_RB + (t - 160)] = rbg[t - 160];
    else if (t < 352)  sm[OFF_PW + (t - 320)] = pwg[t - 320];
    else if (t == 352) sm[OFF_PB] = pbg[0];

    for (int i = t; i < 4352 + 10368; i += NTHREADS)  // zero X1 (col pads) + X2 (borders)
        sm[OFF_X1 + i] = 0.f;

    stageW(sm, t, rwg, 0);
    __syncthreads();

    // ---- T[ci][a][j] = sum_dj w1[ci,a,dj] * it_pad[2j-1+dj] (rank-1 separability) ----
    for (int v = t; v < 4096; v += NTHREADS) {
        int ci = v >> 7, a = (v >> 5) & 3, j = v & 31;
        float acc = 0.f;
#pragma unroll
        for (int dj = 0; dj < 4; ++dj) {
            int col = 2 * j - 1 + dj;
            float itv = (col >= 0 && col < 64) ? sm[OFF_IT + col] : 0.f;
            acc = fmaf(w1g[ci * 16 + a * 4 + dj], itv, acc);
        }
        sm[OFF_T + v] = acc;
    }
    __syncthreads();

    // ---- strip loop: rebuild 4 conv1 rows, then conv2 output row p ----
    const int co2 = t & 31, q2 = t >> 5;  // conv2: one output (co2, q2) per thread
    for (int p = 0; p < 16; ++p) {
        for (int v = t; v < 4096; v += NTHREADS) {
            int ci = v >> 7, r = (v >> 5) & 3, j = v & 31;
            int i = 2 * p - 1 + r;
            float val = 0.f;
            if (i >= 0 && i < 32) {
                float acc = sm[OFF_B1 + ci];
                int ub = 2 * i - 1;
#pragma unroll
                for (int a = 0; a < 4; ++a) {
                    int m = ub + a;
                    float uv = (m >= 0 && m < 64) ? sm[OFF_U + m] : 0.f;
                    acc = fmaf(uv, sm[OFF_T + (ci * 4 + a) * 32 + j], acc);
                }
                val = fmaxf(acc, 0.f);
            }
            sm[OFF_X1 + (ci * 4 + r) * 34 + j + 1] = val;
        }
        __syncthreads();
        {
            float acc = sm[OFF_RB + co2];
            for (int ci = 0; ci < 32; ++ci) {
#pragma unroll
                for (int a = 0; a < 4; ++a) {
                    const float* wb = &sm[OFF_W + ((ci * 4 + a) * 32 + co2) * 4];
                    const float* xb = &sm[OFF_X1 + (ci * 4 + a) * 34 + 2 * q2];
                    float4 wv = *(const float4*)wb;
                    float2 x0 = *(const float2*)(xb);
                    float2 x1 = *(const float2*)(xb + 2);
                    acc = fmaf(wv.x, x0.x, acc);
                    acc = fmaf(wv.y, x0.y, acc);
                    acc = fmaf(wv.z, x1.x, acc);
                    acc = fmaf(wv.w, x1.y, acc);
                }
            }
            sm[OFF_X2 + (co2 * 18 + p + 1) * 18 + q2 + 1] = fmaxf(acc, 0.f);
        }
        __syncthreads();
    }

    // ---- tail layers: stage weights, zero aliased padded buffers, conv3..6, predict ----
    stageW(sm, t, rwg, 1);
    for (int i = t; i < 4096 + 4352; i += NTHREADS)  // zero X3 (over T) + X4/X5/X6 (over X1)
        sm[OFF_T + i] = 0.f;
    __syncthreads();

    convL<8, 18>(sm, t, OFF_X2, OFF_X3, 32);
    __syncthreads();
    stageW(sm, t, rwg, 2);
    __syncthreads();
    convL<4, 10>(sm, t, OFF_X3, OFF_X4, 64);
    __syncthreads();
    stageW(sm, t, rwg, 3);
    __syncthreads();
    convL<2, 6>(sm, t, OFF_X4, OFF_X5, 96);
    __syncthreads();
    stageW(sm, t, rwg, 4);
    __syncthreads();
    convL<1, 4>(sm, t, OFF_X5, OFF_X6, 128);
    __syncthreads();

    if (t == 0) {
        float z = sm[OFF_PB];
        for (int c = 0; c < 32; ++c)
            z = fmaf(sm[OFF_PW + c], sm[OFF_X6 + c], z);
        out[branch * B + s] = 1.f / (1.f + expf(-z));
    }
}

extern "C" void kernel_launch(void* const* d_in, const int* in_sizes, int n_in,
                              void* d_out, int out_size, void* d_ws, size_t ws_size,
                              hipStream_t stream) {
    const int*   user     = (const int*)d_in[0];
    const int*   item_pos = (const int*)d_in[1];
    const int*   item_neg = (const int*)d_in[2];
    const float* uemb     = (const float*)d_in[3];
    const float* iemb     = (const float*)d_in[4];
    const float* w1       = (const float*)d_in[5];
    const float* b1       = (const float*)d_in[6];
    const float* rw       = (const float*)d_in[7];
    const float* rb       = (const float*)d_in[8];
    const float* pw       = (const float*)d_in[9];
    const float* pb       = (const float*)d_in[10];
    float* out = (float*)d_out;

    const int B = in_sizes[0];  // 4096

    (void)hipFuncSetAttribute((const void*)convncf_fused,
                              hipFuncAttributeMaxDynamicSharedMemorySize, SMEM_BYTES);

    dim3 grid(B, 2);
    convncf_fused<<<grid, NTHREADS, SMEM_BYTES, stream>>>(
        user, item_pos, item_neg, uemb, iemb, w1, b1, rw, rb, pw, pb, out, B);
}

// Round 2
// 600.738 us; speedup vs baseline: 9.0253x; 9.0253x over previous
//
#include <hip/hip_runtime.h>
#include <math.h>

#define NT 512

typedef __attribute__((ext_vector_type(8))) short short8;
typedef __attribute__((ext_vector_type(4))) float f32x4;

// ---- LDS arena byte offsets ----
#define U_OFF    0        // 64 f32
#define IT_OFF   256      // 64 f32
#define B1_OFF   512      // 32 f32
#define RB_OFF   640      // 160 f32
#define PW_OFF   1280     // 32 f32
#define PBIAS_OFF 1408    // 1 f32 (pad to 16)
#define W1_OFF   1424     // 512 f32 transposed [tap][c] -> end 3472, pad 3584
#define WB_OFF   3584     // 16384 bf16 shorts = 32768 B -> end 36352
#define T_OFF    36352    // T[a][j][ci] f32, row stride 144 B, 4*32*144 = 18432
#define X2_OFF   36352    // f32 [18][18][32], row stride 2320 -> 41760, end 78112
#define X1_OFF   78112    // bf16 [34][34][32], row stride 2192 -> 74528, end 152640
#define X3_OFF   X1_OFF             // f32 [10][10][32] stride 1296 = 12960
#define X4_OFF   (X1_OFF + 12960)   // f32 [6][6][32]  stride 784  = 4704
#define X5_OFF   (X1_OFF + 17664)   // f32 [4][4][32]  stride 528  = 2112
#define X6_OFF   (X1_OFF + 19776)   // 32 f32 = 128
#define SMEM_BYTES 152640

#define X1_STRIDE 2192   // 34*64 + 16  (== 16 mod 128)
#define X2_STRIDE 2320   // 18*128 + 16
#define X3_STRIDE 1296   // 10*128 + 16
#define X4_STRIDE 784    // 6*128 + 16
#define X5_STRIDE 528    // 4*128 + 16

__device__ __forceinline__ unsigned short f2bf(float f) {   // RNE f32->bf16
    unsigned int x = __float_as_uint(f);
    x += 0x7fffu + ((x >> 16) & 1u);
    return (unsigned short)(x >> 16);
}

// stage layer-L weights into LDS as bf16 [tap][co][ci]
__device__ __forceinline__ void stageWb(char* smb, int t, const float* __restrict__ rwg,
                                        const unsigned short* __restrict__ wsbf, int useWs, int L) {
    if (useWs) {
        const float4* src = (const float4*)(wsbf + L * 16384);  // pre-converted bf16
        for (int k = t; k < 2048; k += NT)
            *(float4*)(smb + WB_OFF + k * 16) = src[k];
    } else {
        for (int k = t; k < 2048; k += NT) {
            int ci0 = (k & 3) * 8, co = (k >> 2) & 31, tap = k >> 7;
            union { short8 s; unsigned short u[8]; } cv;
#pragma unroll
            for (int e = 0; e < 8; ++e)
                cv.u[e] = f2bf(rwg[((L * 32 + co) * 32 + ci0 + e) * 16 + tap]);
            *(short8*)(smb + WB_OFF + k * 16) = cv.s;
        }
    }
}

// One conv layer as 16 tap-GEMMs via mfma_f32_16x16x32_bf16.
// M = PB*QB spatial outputs enumerated m = q*PB + p; N = 32 (co); K = 32 (ci) per tap.
// Src tensor: [row][col][ci] (bf16 if SRC_BF16 else f32), XOR-swizzled (bit4 ^= row bit3).
// Dst tensor: f32 [row][col][ci], interior written at (p+1, q+1).
template<int PB, int QB, bool SRC_BF16, int IN_STRIDE, int OUT_STRIDE>
__device__ __forceinline__ void convLayer(char* smb, int inOff, int outOff, int L) {
    const int t = threadIdx.x;
    const int w = t >> 6, l = t & 63;
    const int n = l & 15, g = l >> 4;
    constexpr int MT = (PB * QB + 15) / 16;
    const int nt = w & 1;
    const float* smf = (const float*)smb;

    short8 bfr[16];                       // B-frags for all 16 taps, held in regs
#pragma unroll
    for (int tap = 0; tap < 16; ++tap)
        bfr[tap] = *(const short8*)(smb + WB_OFF + tap * 2048 + (nt * 16 + n) * 64 + g * 16);
    const float bias = smf[RB_OFF / 4 + L * 32 + nt * 16 + n];

    for (int tile = w; tile < 2 * MT; tile += 8) {   // step 8 keeps nt parity
        const int mt = tile >> 1;
        f32x4 acc = {bias, bias, bias, bias};
        const int ml = l & 15;                        // A row within tile
        const int p = ml % PB;
        const int qq = mt * (16 / PB) + ml / PB;
        const bool valid = (qq < QB);
#pragma unroll
        for (int a = 0; a < 4; ++a) {
#pragma unroll
            for (int dj = 0; dj < 4; ++dj) {
                const int row = valid ? (2 * p + a) : 0;   // invalid lanes read border zeros
                const int col = valid ? (2 * qq + dj) : 0;
                short8 af;
                if constexpr (SRC_BF16) {
                    unsigned addr = (unsigned)(inOff + row * IN_STRIDE + col * 64 + g * 16);
                    addr ^= (unsigned)(((row >> 3) & 1) << 4);
                    af = *(const short8*)(smb + addr);
                } else {
                    unsigned addr0 = (unsigned)(inOff + row * IN_STRIDE + col * 128 + g * 32);
                    unsigned sw = (unsigned)(((row >> 3) & 1) << 4);
                    float4 lo = *(const float4*)(smb + (addr0 ^ sw));
                    float4 hi = *(const float4*)(smb + ((addr0 + 16) ^ sw));
                    union { short8 s; unsigned short u[8]; } cv;
                    cv.u[0] = f2bf(lo.x); cv.u[1] = f2bf(lo.y); cv.u[2] = f2bf(lo.z); cv.u[3] = f2bf(lo.w);
                    cv.u[4] = f2bf(hi.x); cv.u[5] = f2bf(hi.y); cv.u[6] = f2bf(hi.z); cv.u[7] = f2bf(hi.w);
                    af = cv.s;
                }
                acc = __builtin_amdgcn_mfma_f32_16x16x32_bf16(af, bfr[a * 4 + dj], acc, 0, 0, 0);
            }
        }
#pragma unroll
        for (int vi = 0; vi < 4; ++vi) {              // D: col=lane&15, row=(lane>>4)*4+vi
            const int mo = g * 4 + vi;
            const int po = mo % PB;
            const int qo = mt * (16 / PB) + mo / PB;
            if (qo < QB) {
                float v = fmaxf(acc[vi], 0.f);
                unsigned addr = (unsigned)(outOff + (po + 1) * OUT_STRIDE + (qo + 1) * 128 + (nt * 16 + n) * 4);
                addr ^= (unsigned)((((po + 1) >> 3) & 1) << 4);
                *(float*)(smb + addr) = v;
            }
        }
    }
}

// pre-convert rest_w (f32 [L][co][ci][a][dj]) -> d_ws bf16 [L][tap][co][ci]
__global__ void preconv_w(const float* __restrict__ rwg, unsigned short* __restrict__ wsbf) {
    int idx = blockIdx.x * 256 + threadIdx.x;
    if (idx < 81920) {
        int ci = idx & 31, co = (idx >> 5) & 31, tap = (idx >> 10) & 15, L = idx >> 14;
        wsbf[idx] = f2bf(rwg[(((L * 32 + co) * 32 + ci) << 4) + tap]);
    }
}

__global__ void __launch_bounds__(NT, 1)
convncf_main(const int* __restrict__ user, const int* __restrict__ item_pos,
             const int* __restrict__ item_neg,
             const float* __restrict__ uemb, const float* __restrict__ iemb,
             const float* __restrict__ w1g, const float* __restrict__ b1g,
             const float* __restrict__ rwg, const float* __restrict__ rbg,
             const float* __restrict__ pwg, const float* __restrict__ pbg,
             const unsigned short* __restrict__ wsbf, int useWs,
             float* __restrict__ out, int B)
{
    extern __shared__ char smb[];
    float* smf = (float*)smb;
    const int t = threadIdx.x;
    const int s = blockIdx.x;
    const int branch = blockIdx.y;
    const int uidx = user[s];
    const int iidx = branch ? item_neg[s] : item_pos[s];
    const float4 zero4 = make_float4(0.f, 0.f, 0.f, 0.f);

    // ---- P0: consts + Wb2 staging + zero X2/X1 regions ----
    if (t < 64)        smf[U_OFF/4 + t]        = uemb[(long)uidx * 64 + t];
    else if (t < 128)  smf[IT_OFF/4 + t - 64]  = iemb[(long)iidx * 64 + t - 64];
    else if (t < 160)  smf[B1_OFF/4 + t - 128] = b1g[t - 128];
    else if (t < 320)  smf[RB_OFF/4 + t - 160] = rbg[t - 160];
    else if (t < 352)  smf[PW_OFF/4 + t - 320] = pwg[t - 320];
    else if (t == 352) smf[PBIAS_OFF/4] = pbg[0];
    {   // w1 transposed: w1s[tap*32 + c] = w1g[c*16 + tap]
        int c = t & 31, tap = t >> 5;
        smf[W1_OFF/4 + t] = w1g[c * 16 + tap];
    }
    stageWb(smb, t, rwg, wsbf, useWs, 0);
    for (int k = t; k < (SMEM_BYTES - T_OFF) / 16; k += NT)
        *(float4*)(smb + T_OFF + k * 16) = zero4;
    __syncthreads();

    // ---- P1: T[a][j][ci] = sum_dj w1[ci,a,dj] * it_pad[2j-1+dj] ----
    for (int v = t; v < 4096; v += NT) {
        int ci = v & 31, j = (v >> 5) & 31, a = v >> 10;
        float acc = 0.f;
#pragma unroll
        for (int dj = 0; dj < 4; ++dj) {
            int c = 2 * j - 1 + dj;
            float itv = (c >= 0 && c < 64) ? smf[IT_OFF/4 + c] : 0.f;
            acc = fmaf(smf[W1_OFF/4 + (a * 4 + dj) * 32 + ci], itv, acc);
        }
        *(float*)(smb + T_OFF + (a * 32 + j) * 144 + ci * 4) = acc;
    }
    __syncthreads();

    // ---- P2: X1 interior [i+1][j+1][ci] bf16, swizzled ----
    for (int v = t; v < 4096; v += NT) {
        int i = v & 31, j = (v >> 5) & 31, cg = v >> 10;   // i fastest: T reads broadcast
        float acc[8];
        {
            const float* b1p = smf + B1_OFF/4 + cg * 8;
#pragma unroll
            for (int e = 0; e < 8; ++e) acc[e] = b1p[e];
        }
#pragma unroll
        for (int a = 0; a < 4; ++a) {
            int m = 2 * i - 1 + a;
            float uv = (m >= 0 && m < 64) ? smf[U_OFF/4 + m] : 0.f;
            const float* tp = (const float*)(smb + T_OFF + (a * 32 + j) * 144 + cg * 32);
            float4 t0 = *(const float4*)tp;
            float4 t1 = *(const float4*)(tp + 4);
            acc[0] = fmaf(uv, t0.x, acc[0]); acc[1] = fmaf(uv, t0.y, acc[1]);
            acc[2] = fmaf(uv, t0.z, acc[2]); acc[3] = fmaf(uv, t0.w, acc[3]);
            acc[4] = fmaf(uv, t1.x, acc[4]); acc[5] = fmaf(uv, t1.y, acc[5]);
            acc[6] = fmaf(uv, t1.z, acc[6]); acc[7] = fmaf(uv, t1.w, acc[7]);
        }
        union { short8 sv; unsigned short u[8]; } cv;
#pragma unroll
        for (int e = 0; e < 8; ++e) cv.u[e] = f2bf(fmaxf(acc[e], 0.f));
        unsigned addr = (unsigned)(X1_OFF + (i + 1) * X1_STRIDE + (j + 1) * 64 + cg * 16);
        addr ^= (unsigned)((((i + 1) >> 3) & 1) << 4);
        *(short8*)(smb + addr) = cv.sv;
    }
    __syncthreads();

    // ---- P3: zero X2 borders (T is dead now) + conv2 ----
    for (int k = t; k < 290; k += NT) {               // rows 0 and 17, full rows
        int r = (k < 145) ? 0 : 17;
        int kk = (k < 145) ? k : k - 145;
        *(float4*)(smb + X2_OFF + r * X2_STRIDE + kk * 16) = zero4;
    }
    for (int k = t; k < 256; k += NT) {               // cols 0 and 17, rows 1..16
        int gg = k & 7, cc = (k >> 3) & 1, r = 1 + (k >> 4);
        *(float4*)(smb + X2_OFF + r * X2_STRIDE + (cc ? 17 : 0) * 128 + gg * 16) = zero4;
    }
    convLayer<16, 16, true, X1_STRIDE, X2_STRIDE>(smb, X1_OFF, X2_OFF, 0);
    __syncthreads();

    // ---- P4: stage Wb3 + zero X3..X6 (X1 region now dead) ----
    stageWb(smb, t, rwg, wsbf, useWs, 1);
    for (int k = t; k < 1244; k += NT)
        *(float4*)(smb + X3_OFF + k * 16) = zero4;
    __syncthreads();

    convLayer<8, 8, false, X2_STRIDE, X3_STRIDE>(smb, X2_OFF, X3_OFF, 1);
    __syncthreads();
    stageWb(smb, t, rwg, wsbf, useWs, 2);
    __syncthreads();
    convLayer<4, 4, false, X3_STRIDE, X4_STRIDE>(smb, X3_OFF, X4_OFF, 2);
    __syncthreads();
    stageWb(smb, t, rwg, wsbf, useWs, 3);
    __syncthreads();
    convLayer<2, 2, false, X4_STRIDE, X5_STRIDE>(smb, X4_OFF, X5_OFF, 3);
    __syncthreads();
    stageWb(smb, t, rwg, wsbf, useWs, 4);
    __syncthreads();
    convLayer<1, 1, false, X5_STRIDE, 0>(smb, X5_OFF, X6_OFF - 128, 4);
    __syncthreads();

    // ---- P12: prediction head ----
    if (t == 0) {
        float z = smf[PBIAS_OFF/4];
#pragma unroll
        for (int c = 0; c < 32; ++c)
            z = fmaf(smf[PW_OFF/4 + c], smf[X6_OFF/4 + c], z);
        out[branch * B + s] = 1.f / (1.f + expf(-z));
    }
}

extern "C" void kernel_launch(void* const* d_in, const int* in_sizes, int n_in,
                              void* d_out, int out_size, void* d_ws, size_t ws_size,
                              hipStream_t stream) {
    const int*   user     = (const int*)d_in[0];
    const int*   item_pos = (const int*)d_in[1];
    const int*   item_neg = (const int*)d_in[2];
    const float* uemb     = (const float*)d_in[3];
    const float* iemb     = (const float*)d_in[4];
    const float* w1       = (const float*)d_in[5];
    const float* b1       = (const float*)d_in[6];
    const float* rw       = (const float*)d_in[7];
    const float* rb       = (const float*)d_in[8];
    const float* pw       = (const float*)d_in[9];
    const float* pb       = (const float*)d_in[10];
    float* out = (float*)d_out;
    const int B = in_sizes[0];   // 4096

    int useWs = (ws_size >= 81920u * sizeof(unsigned short)) ? 1 : 0;
    unsigned short* wsbf = (unsigned short*)d_ws;
    if (useWs)
        preconv_w<<<dim3(320), dim3(256), 0, stream>>>(rw, wsbf);

    (void)hipFuncSetAttribute((const void*)convncf_main,
                              hipFuncAttributeMaxDynamicSharedMemorySize, SMEM_BYTES);
    dim3 grid(B, 2);
    convncf_main<<<grid, NT, SMEM_BYTES, stream>>>(
        user, item_pos, item_neg, uemb, iemb, w1, b1, rw, rb, pw, pb,
        wsbf, useWs, out, B);
}

// Round 4
// 519.247 us; speedup vs baseline: 10.4418x; 1.1569x over previous
//
#include <hip/hip_runtime.h>
#include <math.h>

#define NT 512

typedef __attribute__((ext_vector_type(8))) short short8;
typedef __attribute__((ext_vector_type(4))) float f32x4;

// ---- LDS arena byte offsets ----
#define U_OFF     0        // 64 f32
#define IT_OFF    256      // 64 f32
#define B1_OFF    512      // 32 f32
#define RB_OFF    640      // 160 f32
#define PW_OFF    1280     // 32 f32
#define PBI_OFF   1408     // 1 f32
#define X1_OFF    1536     // bf16 [34][34][32] row stride 2192 -> 74528 B
#define X1_STR    2192
#define X2_OFF    76064    // bf16 [18][18][32] stride 1168 -> 21024 B
#define X2_STR    1168
#define T_OFF     76064    // alias over X2 (dead after P2): f32 [4][32][ci32] stride 144
#define X3_OFF    97088    // bf16 [10][10][32] stride 656 -> 6560
#define X3_STR    656
#define X4_OFF    103648   // bf16 [6][6][32] stride 400 -> 2400
#define X4_STR    400
#define X5_OFF    106048   // bf16 [4][4][32] stride 272 -> 1088
#define X5_STR    272
#define X6_OFF    107136   // 32 f32 = 128
#define SMEM_BYTES 107264

__device__ __forceinline__ unsigned short f2bf(float f) {   // RNE f32->bf16
    unsigned int x = __float_as_uint(f);
    x += 0x7fffu + ((x >> 16) & 1u);
    return (unsigned short)(x >> 16);
}

// B-frags for mfma_f32_16x16x32_bf16 (VERIFIED mapping, Round 2):
// lane l: col n = l&15 (co = nt*16+n), k = (l>>4)*8 + e.  ws: bf16 [L][tap][co][ci].
__device__ __forceinline__ void loadB16(short8 bfr[16], const unsigned short* __restrict__ wsbf,
                                        const float* __restrict__ rwg, int useWs,
                                        int L, int co, int g) {
    if (useWs) {
        const unsigned short* base = wsbf + L * 16384 + co * 32 + g * 8;
#pragma unroll
        for (int tap = 0; tap < 16; ++tap)
            bfr[tap] = *(const short8*)(base + tap * 1024);
    } else {  // fallback: gather f32 weights from rwg [L][co][ci][tap], convert in regs
#pragma unroll
        for (int tap = 0; tap < 16; ++tap) {
            union { short8 s; unsigned short u[8]; } cv;
#pragma unroll
            for (int e = 0; e < 8; ++e)
                cv.u[e] = f2bf(rwg[((L * 32 + co) * 32 + g * 8 + e) * 16 + tap]);
            bfr[tap] = cv.s;
        }
    }
}

// One conv layer as 16 tap-GEMMs via mfma_f32_16x16x32_bf16 (Round-2-verified
// mappings). A: lane row ml=l&15 -> (p,q), k=(l>>4)*8+e. C/D: col=l&15,
// row=(l>>4)*4+vi. Src/dst bf16 [row][col][32ci], XOR-swizzle byte bit4 ^= row bit3.
template<int PB, int QB, int INS, int OUTS, bool LAST>
__device__ __forceinline__ void conv16(char* smb, int inOff, int outOff,
                                       const short8 bfr[16], float bias) {
    const int t = threadIdx.x;
    const int w = t >> 6, l = t & 63;
    const int n = l & 15, g = l >> 4, nt = w & 1;
    constexpr int MT = (PB * QB + 15) / 16;
    for (int tile = w; tile < 2 * MT; tile += 8) {   // step 8 keeps tile&1 == nt
        const int mt = tile >> 1;
        f32x4 acc = {bias, bias, bias, bias};
        const int ml = l & 15;
        const int p = ml % PB;
        const int qq = mt * (16 / PB) + ml / PB;
        const bool valid = (qq < QB);
#pragma unroll
        for (int a = 0; a < 4; ++a)
#pragma unroll
            for (int dj = 0; dj < 4; ++dj) {
                const int row = valid ? (2 * p + a) : 0;   // invalid lanes read border zeros
                const int col = valid ? (2 * qq + dj) : 0;
                unsigned addr = (unsigned)(inOff + row * INS + col * 64 + g * 16);
                addr ^= (unsigned)(((row >> 3) & 1) << 4);
                short8 af = *(const short8*)(smb + addr);
                acc = __builtin_amdgcn_mfma_f32_16x16x32_bf16(af, bfr[a * 4 + dj], acc, 0, 0, 0);
            }
#pragma unroll
        for (int vi = 0; vi < 4; ++vi) {
            const int mo = g * 4 + vi;
            const int po = mo % PB;
            const int qo = mt * (16 / PB) + mo / PB;
            if (qo < QB) {
                const float v = fmaxf(acc[vi], 0.f);
                if constexpr (LAST) {                 // conv6: qo<1 => mo==0; write X6 f32
                    *(float*)(smb + outOff + (nt * 16 + n) * 4) = v;
                } else {
                    const int rowo = po + 1;
                    unsigned addr = (unsigned)(outOff + rowo * OUTS + (qo + 1) * 64 + (nt * 16 + n) * 2);
                    addr ^= (unsigned)(((rowo >> 3) & 1) << 4);
                    *(unsigned short*)(smb + addr) = f2bf(v);
                }
            }
        }
    }
}

// pre-convert rest_w (f32 [L][co][ci][a][dj]) -> d_ws bf16 [L][tap][co][ci]
__global__ void preconv_w(const float* __restrict__ rwg, unsigned short* __restrict__ wsbf) {
    int idx = blockIdx.x * 256 + threadIdx.x;
    if (idx < 81920) {
        int ci = idx & 31, co = (idx >> 5) & 31, tap = (idx >> 10) & 15, L = idx >> 14;
        wsbf[idx] = f2bf(rwg[(((L * 32 + co) * 32 + ci) << 4) + tap]);
    }
}

__global__ void __launch_bounds__(NT, 2)
convncf_main(const int* __restrict__ user, const int* __restrict__ item_pos,
             const int* __restrict__ item_neg,
             const float* __restrict__ uemb, const float* __restrict__ iemb,
             const float* __restrict__ w1g, const float* __restrict__ b1g,
             const float* __restrict__ rwg, const float* __restrict__ rbg,
             const float* __restrict__ pwg, const float* __restrict__ pbg,
             const unsigned short* __restrict__ wsbf, int useWs,
             float* __restrict__ out, int B)
{
    extern __shared__ char smb[];
    float* smf = (float*)smb;
    const int t = threadIdx.x, w = t >> 6, l = t & 63;
    const int co = ((t >> 6) & 1) * 16 + (t & 15);   // this thread's output channel
    const int g = l >> 4;
    const int s = blockIdx.x, branch = blockIdx.y;
    const int uidx = user[s];
    const int iidx = branch ? item_neg[s] : item_pos[s];
    const float4 zero4 = make_float4(0.f, 0.f, 0.f, 0.f);

    short8 bfr[16];
    loadB16(bfr, wsbf, rwg, useWs, 0, co, g);   // conv2 weights: hide under P0-P2

    // ---- P0: consts + embeddings; zero X1 fully (incl. borders) ----
    if (t < 64)        smf[U_OFF/4 + t]        = uemb[(long)uidx * 64 + t];
    else if (t < 128)  smf[IT_OFF/4 + t - 64]  = iemb[(long)iidx * 64 + t - 64];
    else if (t < 160)  smf[B1_OFF/4 + t - 128] = b1g[t - 128];
    else if (t < 320)  smf[RB_OFF/4 + t - 160] = rbg[t - 160];
    else if (t < 352)  smf[PW_OFF/4 + t - 320] = pwg[t - 320];
    else if (t == 352) smf[PBI_OFF/4] = pbg[0];
    for (int k = t; k < 4658; k += NT)           // 74528 B
        *(float4*)(smb + X1_OFF + k * 16) = zero4;
    __syncthreads();

    // ---- P1: T[a][j][ci] = sum_dj w1[ci,a,dj] * it_pad[2j-1+dj] ----
    for (int v = t; v < 4096; v += NT) {
        const int ci = v & 31, j = (v >> 5) & 31, a = v >> 10;
        const float4 wv = *(const float4*)(w1g + ci * 16 + a * 4);
        const int c0 = 2 * j - 1;
        const float i0 = (c0 >= 0) ? smf[IT_OFF/4 + c0] : 0.f;
        const float i1 = smf[IT_OFF/4 + c0 + 1];
        const float i2 = smf[IT_OFF/4 + c0 + 2];
        const float i3 = (c0 + 3 < 64) ? smf[IT_OFF/4 + c0 + 3] : 0.f;
        float acc = wv.x * i0;
        acc = fmaf(wv.y, i1, acc);
        acc = fmaf(wv.z, i2, acc);
        acc = fmaf(wv.w, i3, acc);
        *(float*)(smb + T_OFF + (a * 32 + j) * 144 + ci * 4) = acc;
    }
    __syncthreads();

    // ---- P2: X1 interior (bf16, swizzled) ----
    for (int v = t; v < 4096; v += NT) {
        const int i = v & 31, j = (v >> 5) & 31, cg = v >> 10;
        float acc[8];
        {
            const float* b1p = smf + B1_OFF/4 + cg * 8;
#pragma unroll
            for (int e = 0; e < 8; ++e) acc[e] = b1p[e];
        }
#pragma unroll
        for (int a = 0; a < 4; ++a) {
            const int m = 2 * i - 1 + a;
            const float uv = (m >= 0 && m < 64) ? smf[U_OFF/4 + m] : 0.f;
            const float* tp = (const float*)(smb + T_OFF + (a * 32 + j) * 144 + cg * 32);
            const float4 t0 = *(const float4*)tp;
            const float4 t1 = *(const float4*)(tp + 4);
            acc[0] = fmaf(uv, t0.x, acc[0]); acc[1] = fmaf(uv, t0.y, acc[1]);
            acc[2] = fmaf(uv, t0.z, acc[2]); acc[3] = fmaf(uv, t0.w, acc[3]);
            acc[4] = fmaf(uv, t1.x, acc[4]); acc[5] = fmaf(uv, t1.y, acc[5]);
            acc[6] = fmaf(uv, t1.z, acc[6]); acc[7] = fmaf(uv, t1.w, acc[7]);
        }
        union { short8 sv; unsigned short u[8]; } cv;
#pragma unroll
        for (int e = 0; e < 8; ++e) cv.u[e] = f2bf(fmaxf(acc[e], 0.f));
        unsigned addr = (unsigned)(X1_OFF + (i + 1) * X1_STR + (j + 1) * 64 + cg * 16);
        addr ^= (unsigned)((((i + 1) >> 3) & 1) << 4);
        *(short8*)(smb + addr) = cv.sv;
    }
    __syncthreads();

    // ---- P3a: zero X2..X5 fully (T dead now); barrier removes zero-vs-write races ----
    for (int k = t; k < 1314; k += NT)            // X2: 21024 B
        *(float4*)(smb + X2_OFF + k * 16) = zero4;
    for (int k = t; k < 628; k += NT)             // X3+X4+X5: contiguous 10048 B
        *(float4*)(smb + X3_OFF + k * 16) = zero4;
    __syncthreads();

    // ---- conv chain; next layer's B-frags load before each barrier ----
    conv16<16, 16, X1_STR, X2_STR, false>(smb, X1_OFF, X2_OFF, bfr, smf[RB_OFF/4 + co]);
    loadB16(bfr, wsbf, rwg, useWs, 1, co, g);
    __syncthreads();

    conv16<8, 8, X2_STR, X3_STR, false>(smb, X2_OFF, X3_OFF, bfr, smf[RB_OFF/4 + 32 + co]);
    loadB16(bfr, wsbf, rwg, useWs, 2, co, g);
    __syncthreads();

    conv16<4, 4, X3_STR, X4_STR, false>(smb, X3_OFF, X4_OFF, bfr, smf[RB_OFF/4 + 64 + co]);
    loadB16(bfr, wsbf, rwg, useWs, 3, co, g);
    __syncthreads();

    conv16<2, 2, X4_STR, X5_STR, false>(smb, X4_OFF, X5_OFF, bfr, smf[RB_OFF/4 + 96 + co]);
    loadB16(bfr, wsbf, rwg, useWs, 4, co, g);
    __syncthreads();

    conv16<1, 1, X5_STR, 0, true>(smb, X5_OFF, X6_OFF, bfr, smf[RB_OFF/4 + 128 + co]);
    __syncthreads();

    // ---- head: wave 0 dot(X6, pw) + sigmoid ----
    if (w == 0) {
        float v = (l < 32) ? smf[X6_OFF/4 + l] * smf[PW_OFF/4 + l] : 0.f;
#pragma unroll
        for (int d = 32; d >= 1; d >>= 1) v += __shfl_xor(v, d, 64);
        if (l == 0) {
            const float z = smf[PBI_OFF/4] + v;
            out[branch * B + s] = 1.f / (1.f + expf(-z));
        }
    }
}

extern "C" void kernel_launch(void* const* d_in, const int* in_sizes, int n_in,
                              void* d_out, int out_size, void* d_ws, size_t ws_size,
                              hipStream_t stream) {
    const int*   user     = (const int*)d_in[0];
    const int*   item_pos = (const int*)d_in[1];
    const int*   item_neg = (const int*)d_in[2];
    const float* uemb     = (const float*)d_in[3];
    const float* iemb     = (const float*)d_in[4];
    const float* w1       = (const float*)d_in[5];
    const float* b1       = (const float*)d_in[6];
    const float* rw       = (const float*)d_in[7];
    const float* rb       = (const float*)d_in[8];
    const float* pw       = (const float*)d_in[9];
    const float* pb       = (const float*)d_in[10];
    float* out = (float*)d_out;
    const int B = in_sizes[0];   // 4096

    const int useWs = (ws_size >= 81920u * sizeof(unsigned short)) ? 1 : 0;
    unsigned short* wsbf = (unsigned short*)d_ws;
    if (useWs)
        preconv_w<<<dim3(320), dim3(256), 0, stream>>>(rw, wsbf);

    (void)hipFuncSetAttribute((const void*)convncf_main,
                              hipFuncAttributeMaxDynamicSharedMemorySize, SMEM_BYTES);
    dim3 grid(B, 2);
    convncf_main<<<grid, NT, SMEM_BYTES, stream>>>(
        user, item_pos, item_neg, uemb, iemb, w1, b1, rw, rb, pw, pb,
        wsbf, useWs, out, B);
}